// Round 2
// baseline (555.719 us; speedup 1.0000x reference)
//
#include <hip/hip_runtime.h>
#include <hip/hip_bf16.h>

// MLA forward, MI355X baseline (round 1: workspace aliasing, no memset API).
// B=2 S=2048 D=2048 H=16 NOPE=128 ROPE=64 VH=128 QR=KVR=512
// All matmuls as bf16 MFMA (16x16x32), fp32 accumulate; softmax fp32.

typedef __attribute__((ext_vector_type(8))) short s8v;   // 8 bf16 (4 VGPR)
typedef __attribute__((ext_vector_type(4))) float f4v;   // 4 fp32 acc

#define DEV static __device__ __forceinline__

DEV ushort f2b(float f) {
  __hip_bfloat16 h = __float2bfloat16(f);
  return *reinterpret_cast<ushort*>(&h);
}
DEV float b2f(ushort u) {
  __hip_bfloat16 h = *reinterpret_cast<__hip_bfloat16*>(&u);
  return __bfloat162float(h);
}
DEV f4v mfma16(s8v a, s8v b, f4v c) {
  return __builtin_amdgcn_mfma_f32_16x16x32_bf16(a, b, c, 0, 0, 0);
}

// ---------------------------------------------------------------- cast f32->bf16
__global__ void cast_f2b_kernel(const float* __restrict__ src, ushort* __restrict__ dst, int n4) {
  int i = blockIdx.x * 256 + threadIdx.x;
  if (i >= n4) return;
  float4 v = reinterpret_cast<const float4*>(src)[i];
  ushort4 o;
  o.x = f2b(v.x); o.y = f2b(v.y); o.z = f2b(v.z); o.w = f2b(v.w);
  reinterpret_cast<ushort4*>(dst)[i] = o;
}

// zero-fill (replaces hipMemsetAsync; graph-capture-safe by construction)
__global__ void fill_zero_kernel(ushort* __restrict__ dst, int n8) {
  int i = blockIdx.x * 256 + threadIdx.x;
  if (i >= n8) return;
  reinterpret_cast<uint4*>(dst)[i] = uint4{0u, 0u, 0u, 0u};
}

// ---------------------------------------------------------------- GEMM C = A * B^T
// A: MxK bf16 row-major, B: NxK bf16 row-major, C: MxN (fp32 or bf16).
// 128x128 block tile, 4 waves (2x2), each wave 64x64 = 4x4 MFMA frags.
template <bool BF16OUT>
__global__ __launch_bounds__(256) void gemm_bt(const ushort* __restrict__ A,
                                               const ushort* __restrict__ B,
                                               void* __restrict__ C,
                                               int M, int N, int K) {
  __shared__ ushort a_lds[128][40];  // 32 K + 8 pad (80B rows: 16B-aligned, 2-way bank max)
  __shared__ ushort b_lds[128][40];
  const int tid = threadIdx.x;
  const int lane = tid & 63, wv = tid >> 6;
  const int wm = wv >> 1, wn = wv & 1;
  const int l15 = lane & 15, l4 = lane >> 4;
  const int row0 = blockIdx.x * 128, col0 = blockIdx.y * 128;

  f4v acc[4][4];
#pragma unroll
  for (int i = 0; i < 4; ++i)
#pragma unroll
    for (int j = 0; j < 4; ++j) acc[i][j] = f4v{0.f, 0.f, 0.f, 0.f};

  for (int k0 = 0; k0 < K; k0 += 32) {
    __syncthreads();
#pragma unroll
    for (int it = 0; it < 2; ++it) {
      int c = tid + it * 256;          // 512 chunks of 8 bf16 per matrix
      int r = c >> 2, cc = (c & 3) * 8;
      *reinterpret_cast<uint4*>(&a_lds[r][cc]) =
          *reinterpret_cast<const uint4*>(&A[(size_t)(row0 + r) * K + k0 + cc]);
      *reinterpret_cast<uint4*>(&b_lds[r][cc]) =
          *reinterpret_cast<const uint4*>(&B[(size_t)(col0 + r) * K + k0 + cc]);
    }
    __syncthreads();
    s8v af[4], bfr[4];
#pragma unroll
    for (int mi = 0; mi < 4; ++mi)
      af[mi] = *reinterpret_cast<const s8v*>(&a_lds[wm * 64 + mi * 16 + l15][8 * l4]);
#pragma unroll
    for (int ni = 0; ni < 4; ++ni)
      bfr[ni] = *reinterpret_cast<const s8v*>(&b_lds[wn * 64 + ni * 16 + l15][8 * l4]);
#pragma unroll
    for (int mi = 0; mi < 4; ++mi)
#pragma unroll
      for (int ni = 0; ni < 4; ++ni) acc[mi][ni] = mfma16(af[mi], bfr[ni], acc[mi][ni]);
  }

#pragma unroll
  for (int mi = 0; mi < 4; ++mi)
#pragma unroll
    for (int ni = 0; ni < 4; ++ni)
#pragma unroll
      for (int j = 0; j < 4; ++j) {
        int r = row0 + wm * 64 + mi * 16 + l4 * 4 + j;   // C/D: row=(lane>>4)*4+reg
        int cl = col0 + wn * 64 + ni * 16 + l15;          //      col=lane&15
        if (BF16OUT)
          reinterpret_cast<ushort*>(C)[(size_t)r * N + cl] = f2b(acc[mi][ni][j]);
        else
          reinterpret_cast<float*>(C)[(size_t)r * N + cl] = acc[mi][ni][j];
      }
}

// ---------------------------------------------------------------- RMSNorm(cq,ckv) + RoPE(k_rope)
// g1: 4096 x 1152 fp32 (cols 0-511 cq | 512-1023 ckv | 1024-1087 krope | pad)
__global__ __launch_bounds__(256) void norm_rope1_kernel(
    const float* __restrict__ g1, const float* __restrict__ wq, const float* __restrict__ wkv,
    const float* __restrict__ freqs, ushort* __restrict__ nq, ushort* __restrict__ nkv,
    ushort* __restrict__ kro) {
  const int m = blockIdx.x;       // 0..4095 = b*2048+s
  const int s = m & 2047;
  const int tid = threadIdx.x;
  __shared__ float red[4];
  const float* row = g1 + (size_t)m * 1152;

  float v0 = row[tid], v1 = row[tid + 256];
  float ss = v0 * v0 + v1 * v1;
#pragma unroll
  for (int off = 32; off > 0; off >>= 1) ss += __shfl_down(ss, off);
  if ((tid & 63) == 0) red[tid >> 6] = ss;
  __syncthreads();
  float r = rsqrtf((red[0] + red[1] + red[2] + red[3]) * (1.0f / 512.0f) + 1e-6f);
  nq[(size_t)m * 512 + tid] = f2b(v0 * r * wq[tid]);
  nq[(size_t)m * 512 + tid + 256] = f2b(v1 * r * wq[tid + 256]);

  float u0 = row[512 + tid], u1 = row[512 + tid + 256];
  float ss2 = u0 * u0 + u1 * u1;
#pragma unroll
  for (int off = 32; off > 0; off >>= 1) ss2 += __shfl_down(ss2, off);
  __syncthreads();   // all reads of red done before overwrite
  if ((tid & 63) == 0) red[tid >> 6] = ss2;
  __syncthreads();
  float r2 = rsqrtf((red[0] + red[1] + red[2] + red[3]) * (1.0f / 512.0f) + 1e-6f);
  nkv[(size_t)m * 512 + tid] = f2b(u0 * r2 * wkv[tid]);
  nkv[(size_t)m * 512 + tid + 256] = f2b(u1 * r2 * wkv[tid + 256]);

  if (tid < 32) {  // shared rope key: rotate + 1/H scale
    float x0 = row[1024 + 2 * tid], x1 = row[1024 + 2 * tid + 1];
    float c = freqs[s * 64 + 2 * tid], sn = freqs[s * 64 + 2 * tid + 1];
    kro[(size_t)m * 64 + 2 * tid] = f2b((x0 * c - x1 * sn) * (1.0f / 16.0f));
    kro[(size_t)m * 64 + 2 * tid + 1] = f2b((x0 * sn + x1 * c) * (1.0f / 16.0f));
  }
}

// ---------------------------------------------------------------- RoPE on q_rope (in-place, g2q cols 2048+h*64+2j)
__global__ void rope_q_kernel(ushort* __restrict__ g2q, const float* __restrict__ freqs) {
  int idx = blockIdx.x * 256 + threadIdx.x;  // 4096*16*32
  int m = idx >> 9;
  int rem = idx & 511;
  int h = rem >> 5, j = rem & 31;
  int s = m & 2047;
  size_t base = (size_t)m * 3072 + 2048 + h * 64 + 2 * j;
  ushort2 pr = *reinterpret_cast<ushort2*>(&g2q[base]);
  float x0 = b2f(pr.x), x1 = b2f(pr.y);
  float c = freqs[s * 64 + 2 * j], sn = freqs[s * 64 + 2 * j + 1];
  ushort2 o;
  o.x = f2b(x0 * c - x1 * sn);
  o.y = f2b(x0 * sn + x1 * c);
  *reinterpret_cast<ushort2*>(&g2q[base]) = o;
}

// ---------------------------------------------------------------- V transpose: g2kv v-section -> vT (B,H,128,S)
__global__ __launch_bounds__(256) void transpose_v_kernel(const ushort* __restrict__ g2kv,
                                                          ushort* __restrict__ vT) {
  int blk = blockIdx.x;          // B*H * (S/64) * (128/64) = 2048
  int bh = blk >> 6;
  int rem = blk & 63;
  int st = rem >> 1, dt = rem & 1;
  int b = bh >> 4, h = bh & 15;
  __shared__ ushort t[64][72];
  int tid = threadIdx.x;
#pragma unroll
  for (int it = 0; it < 2; ++it) {
    int c = tid + it * 256;
    int sl = c >> 3, cc = (c & 7) * 8;
    *reinterpret_cast<uint4*>(&t[sl][cc]) = *reinterpret_cast<const uint4*>(
        &g2kv[(size_t)(b * 2048 + st * 64 + sl) * 4096 + 2048 + h * 128 + dt * 64 + cc]);
  }
  __syncthreads();
#pragma unroll
  for (int it = 0; it < 2; ++it) {
    int c = tid + it * 256;
    int dl = c >> 3, cc = (c & 7) * 8;
    ushort tmp[8];
#pragma unroll
    for (int e = 0; e < 8; ++e) tmp[e] = t[cc + e][dl];
    *reinterpret_cast<uint4*>(&vT[(size_t)(bh * 128 + dt * 64 + dl) * 2048 + st * 64 + cc]) =
        *reinterpret_cast<uint4*>(tmp);
  }
}

// ---------------------------------------------------------------- causal flash attention
// grid (qt=32, bh=32), 256 thr = 4 waves; wave owns 16 q-rows. Q d=192 (128 nope + 64 rope).
__global__ __launch_bounds__(256) void attn_kernel(const ushort* __restrict__ q,      // g2q 4096x3072
                                                   const ushort* __restrict__ knope,  // g2kv 4096x4096
                                                   const ushort* __restrict__ kro,    // 4096x64
                                                   const ushort* __restrict__ vT,     // (B*H*128)x2048
                                                   ushort* __restrict__ out) {        // 4096x2048
  const int qt = blockIdx.x, bh = blockIdx.y;
  const int b = bh >> 4, h = bh & 15;
  const int tid = threadIdx.x, lane = tid & 63, w = tid >> 6;
  const int l15 = lane & 15, l4 = lane >> 4;
  __shared__ ushort k_lds[64][200];     // 64 keys x 192 d (+8 pad)
  __shared__ ushort v_lds[128][72];     // 128 vd  x 64 keys (+8 pad)
  __shared__ ushort p_lds[4][16][72];   // per-wave P: 16 q x 64 keys

  // Q fragments (A-operand): row = lane&15, k contiguous 8 at 8*(lane>>4)
  s8v qf[6];
  {
    const size_t qbase = (size_t)(b * 2048 + qt * 64 + w * 16 + l15) * 3072;
#pragma unroll
    for (int kc = 0; kc < 4; ++kc)
      qf[kc] = *reinterpret_cast<const s8v*>(&q[qbase + h * 128 + kc * 32 + 8 * l4]);
#pragma unroll
    for (int kc = 4; kc < 6; ++kc)
      qf[kc] = *reinterpret_cast<const s8v*>(&q[qbase + 2048 + h * 64 + (kc - 4) * 32 + 8 * l4]);
  }

  f4v oacc[8];
#pragma unroll
  for (int i = 0; i < 8; ++i) oacc[i] = f4v{0.f, 0.f, 0.f, 0.f};
  float m_r[4] = {-INFINITY, -INFINITY, -INFINITY, -INFINITY};
  float l_r[4] = {0.f, 0.f, 0.f, 0.f};
  const float scale = 0.07216878364870323f;  // 1/sqrt(192)

  for (int kt = 0; kt <= qt; ++kt) {
    __syncthreads();
    // stage K tile: 64 keys x 192 (nope from g2kv, rope broadcast from kro)
#pragma unroll
    for (int it = 0; it < 6; ++it) {
      int c = tid + it * 256;        // 64 rows * 24 chunks
      int r = c / 24, cc = c % 24;
      const ushort* src = (cc < 16)
          ? &knope[(size_t)(b * 2048 + kt * 64 + r) * 4096 + h * 128 + cc * 8]
          : &kro[(size_t)(b * 2048 + kt * 64 + r) * 64 + (cc - 16) * 8];
      *reinterpret_cast<uint4*>(&k_lds[r][cc * 8]) = *reinterpret_cast<const uint4*>(src);
    }
    // stage V^T tile: 128 vd x 64 keys
#pragma unroll
    for (int it = 0; it < 4; ++it) {
      int c = tid + it * 256;
      int d = c >> 3, cc = (c & 7) * 8;
      *reinterpret_cast<uint4*>(&v_lds[d][cc]) =
          *reinterpret_cast<const uint4*>(&vT[(size_t)(bh * 128 + d) * 2048 + kt * 64 + cc]);
    }
    __syncthreads();

    // S = Q K^T  (16 q x 64 keys per wave)
    f4v sacc[4];
#pragma unroll
    for (int nb = 0; nb < 4; ++nb) {
      sacc[nb] = f4v{0.f, 0.f, 0.f, 0.f};
#pragma unroll
      for (int kc = 0; kc < 6; ++kc) {
        s8v bfr = *reinterpret_cast<const s8v*>(&k_lds[nb * 16 + l15][kc * 32 + 8 * l4]);
        sacc[nb] = mfma16(qf[kc], bfr, sacc[nb]);
      }
    }
    // scale + causal mask
    const int qrow0 = qt * 64 + w * 16 + l4 * 4;
#pragma unroll
    for (int nb = 0; nb < 4; ++nb) {
      int key = kt * 64 + nb * 16 + l15;
#pragma unroll
      for (int j = 0; j < 4; ++j) {
        float sv = sacc[nb][j] * scale;
        if (kt == qt && key > qrow0 + j) sv = -INFINITY;
        sacc[nb][j] = sv;
      }
    }
    // row max across 64 keys (4 accs + 16-lane butterfly)
    float mx[4];
#pragma unroll
    for (int j = 0; j < 4; ++j)
      mx[j] = fmaxf(fmaxf(sacc[0][j], sacc[1][j]), fmaxf(sacc[2][j], sacc[3][j]));
#pragma unroll
    for (int off = 1; off < 16; off <<= 1)
#pragma unroll
      for (int j = 0; j < 4; ++j) mx[j] = fmaxf(mx[j], __shfl_xor(mx[j], off));
    float al[4], rs[4];
#pragma unroll
    for (int j = 0; j < 4; ++j) {
      float mnew = fmaxf(m_r[j], mx[j]);
      al[j] = __expf(m_r[j] - mnew);
      m_r[j] = mnew;
      rs[j] = 0.f;
    }
#pragma unroll
    for (int nb = 0; nb < 4; ++nb)
#pragma unroll
      for (int j = 0; j < 4; ++j) {
        float p = __expf(sacc[nb][j] - m_r[j]);
        sacc[nb][j] = p;
        rs[j] += p;
      }
#pragma unroll
    for (int off = 1; off < 16; off <<= 1)
#pragma unroll
      for (int j = 0; j < 4; ++j) rs[j] += __shfl_xor(rs[j], off);
#pragma unroll
    for (int j = 0; j < 4; ++j) l_r[j] = l_r[j] * al[j] + rs[j];
    // P -> LDS (transpose acc layout -> A-operand layout)
#pragma unroll
    for (int nb = 0; nb < 4; ++nb)
#pragma unroll
      for (int j = 0; j < 4; ++j)
        p_lds[w][l4 * 4 + j][nb * 16 + l15] = f2b(sacc[nb][j]);
    // rescale O
#pragma unroll
    for (int nv = 0; nv < 8; ++nv)
#pragma unroll
      for (int j = 0; j < 4; ++j) oacc[nv][j] *= al[j];
    // O += P V
#pragma unroll
    for (int kc2 = 0; kc2 < 2; ++kc2) {
      s8v pf = *reinterpret_cast<const s8v*>(&p_lds[w][l15][kc2 * 32 + 8 * l4]);
#pragma unroll
      for (int nv = 0; nv < 8; ++nv) {
        s8v vf = *reinterpret_cast<const s8v*>(&v_lds[nv * 16 + l15][kc2 * 32 + 8 * l4]);
        oacc[nv] = mfma16(pf, vf, oacc[nv]);
      }
    }
  }

  // epilogue: normalize + store (B,S,H*128) bf16
#pragma unroll
  for (int j = 0; j < 4; ++j) {
    float inv = 1.0f / l_r[j];
    int m = b * 2048 + qt * 64 + w * 16 + l4 * 4 + j;
#pragma unroll
    for (int nv = 0; nv < 8; ++nv)
      out[(size_t)m * 2048 + h * 128 + nv * 16 + l15] = f2b(oacc[nv][j] * inv);
  }
}

// ---------------------------------------------------------------- launch
// Workspace layout (lifetime-aliased, peak 96.5 MiB):
//   [ 0,32M)  g2kv (steps 5-8)   overlay: g1 fp32 18M (steps 2-3)
//   [32,56M)  g2q  (steps 4-8)   overlay: xbf 16M @32M, w1 4.5M @48M (steps 0-2)
//   [56,72M)  vT   (steps 7-8)   overlay: nq 4M @56M, nkv 4M @60M, w2q 3M @64M, w2kv 4M @67M
//   [72,88M)  att  (steps 8-9)
//   [88,96M)  wpj  (steps 0-9)
//   [96,96.5M) kro (steps 3-8)
extern "C" void kernel_launch(void* const* d_in, const int* in_sizes, int n_in,
                              void* d_out, int out_size, void* d_ws, size_t ws_size,
                              hipStream_t stream) {
  const float* x       = (const float*)d_in[0];
  const float* freqs   = (const float*)d_in[2];
  const float* w_cq    = (const float*)d_in[3];
  const float* w_qnorm = (const float*)d_in[4];
  const float* w_dqn   = (const float*)d_in[5];
  const float* w_dqr   = (const float*)d_in[6];
  const float* w_ckv   = (const float*)d_in[7];
  const float* w_kvnorm= (const float*)d_in[8];
  const float* w_dkn   = (const float*)d_in[9];
  const float* w_dv    = (const float*)d_in[10];
  const float* w_krope = (const float*)d_in[11];
  const float* w_proj  = (const float*)d_in[12];
  float* out = (float*)d_out;

  char* ws = (char*)d_ws;
  const size_t MB = 1ull << 20;
  ushort* g2kv = (ushort*)(ws + 0);
  float*  g1   = (float*) (ws + 0);
  ushort* g2q  = (ushort*)(ws + 32 * MB);
  ushort* xbf  = (ushort*)(ws + 32 * MB);
  ushort* w1   = (ushort*)(ws + 48 * MB);
  ushort* vT   = (ushort*)(ws + 56 * MB);
  ushort* nq   = (ushort*)(ws + 56 * MB);
  ushort* nkv  = (ushort*)(ws + 60 * MB);
  ushort* w2q  = (ushort*)(ws + 64 * MB);
  ushort* w2kv = (ushort*)(ws + 67 * MB);
  ushort* att  = (ushort*)(ws + 72 * MB);
  ushort* wpj  = (ushort*)(ws + 88 * MB);
  ushort* kro  = (ushort*)(ws + 96 * MB);

  auto cast = [&](const float* s, ushort* d, int n) {
    cast_f2b_kernel<<<(n / 4 + 255) / 256, 256, 0, stream>>>(s, d, n / 4);
  };
  // step 0: casts
  cast(x, xbf, 4096 * 2048);
  cast(w_cq, w1, 512 * 2048);
  cast(w_ckv, w1 + 512 * 2048, 512 * 2048);
  cast(w_krope, w1 + 1024 * 2048, 64 * 2048);
  fill_zero_kernel<<<64, 256, 0, stream>>>(w1 + 1088 * 2048, 64 * 2048 / 8);  // N-pad rows
  cast(w_dqn, w2q, 2048 * 512);
  cast(w_dqr, w2q + 2048 * 512, 1024 * 512);
  cast(w_dkn, w2kv, 2048 * 512);
  cast(w_dv, w2kv + 2048 * 512, 2048 * 512);
  cast(w_proj, wpj, 2048 * 2048);

  // step 2: fused compress GEMM  [cq | ckv | krope]
  gemm_bt<false><<<dim3(32, 9), 256, 0, stream>>>(xbf, w1, g1, 4096, 1152, 2048);
  // step 3: RMSNorm + k_rope RoPE
  norm_rope1_kernel<<<4096, 256, 0, stream>>>(g1, w_qnorm, w_kvnorm, freqs, nq, nkv, kro);
  // step 4: Q decompress
  gemm_bt<true><<<dim3(32, 24), 256, 0, stream>>>(nq, w2q, g2q, 4096, 3072, 512);
  // step 5: KV decompress
  gemm_bt<true><<<dim3(32, 32), 256, 0, stream>>>(nkv, w2kv, g2kv, 4096, 4096, 512);
  // step 6: Q RoPE (in place)
  rope_q_kernel<<<8192, 256, 0, stream>>>(g2q, freqs);
  // step 7: V transpose for attention B-operand
  transpose_v_kernel<<<2048, 256, 0, stream>>>(g2kv, vT);
  // step 8: causal flash attention
  attn_kernel<<<dim3(32, 32), 256, 0, stream>>>(g2q, g2kv, kro, vT, att);
  // step 9: output projection
  gemm_bt<false><<<dim3(32, 16), 256, 0, stream>>>(att, wpj, out, 4096, 2048, 2048);
}

// Round 3
// 420.452 us; speedup vs baseline: 1.3217x; 1.3217x over previous
//
#include <hip/hip_runtime.h>
#include <hip/hip_bf16.h>

// MLA forward, MI355X round 2: global_load_lds staging everywhere, dbuf 2-phase
// pipelines, QBLK=128 8-wave attention with swizzled LDS, LPT causal balance.
// B=2 S=2048 D=2048 H=16 NOPE=128 ROPE=64 VH=128 QR=KVR=512

typedef __attribute__((ext_vector_type(8))) short s8v;   // 8 bf16 (4 VGPR)
typedef __attribute__((ext_vector_type(4))) float f4v;   // 4 fp32 acc

#define DEV static __device__ __forceinline__

DEV ushort f2b(float f) {
  __hip_bfloat16 h = __float2bfloat16(f);
  return *reinterpret_cast<ushort*>(&h);
}
DEV float b2f(ushort u) {
  __hip_bfloat16 h = *reinterpret_cast<__hip_bfloat16*>(&u);
  return __bfloat162float(h);
}
DEV f4v mfma16(s8v a, s8v b, f4v c) {
  return __builtin_amdgcn_mfma_f32_16x16x32_bf16(a, b, c, 0, 0, 0);
}
// async global->LDS, 16B per lane; lds dest = wave-uniform base + lane*16.
DEV void gload16(const ushort* g, ushort* l) {
  __builtin_amdgcn_global_load_lds((const __attribute__((address_space(1))) void*)g,
                                   (__attribute__((address_space(3))) void*)l, 16, 0, 0);
}

// ---------------------------------------------------------------- cast f32->bf16
__global__ void cast_f2b_kernel(const float* __restrict__ src, ushort* __restrict__ dst, int n4) {
  int i = blockIdx.x * 256 + threadIdx.x;
  if (i >= n4) return;
  float4 v = reinterpret_cast<const float4*>(src)[i];
  ushort4 o;
  o.x = f2b(v.x); o.y = f2b(v.y); o.z = f2b(v.z); o.w = f2b(v.w);
  reinterpret_cast<ushort4*>(dst)[i] = o;
}

__global__ void fill_zero_kernel(ushort* __restrict__ dst, int n8) {
  int i = blockIdx.x * 256 + threadIdx.x;
  if (i >= n8) return;
  reinterpret_cast<uint4*>(dst)[i] = uint4{0u, 0u, 0u, 0u};
}

// ---------------------------------------------------------------- GEMM C = A * B^T
// m97-class: 128x128 tile, BK=32, global_load_lds dwordx4 into linear LDS,
// double-buffered, one barrier per K-step. 4 waves (2x2), wave = 64x64 out.
template <bool BF16OUT>
__global__ __launch_bounds__(256) void gemm_bt(const ushort* __restrict__ A,
                                               const ushort* __restrict__ B,
                                               void* __restrict__ C,
                                               int M, int N, int K) {
  __shared__ ushort a_lds[2][128 * 32];   // 8KB per buf, linear (gload_lds dest)
  __shared__ ushort b_lds[2][128 * 32];
  const int tid = threadIdx.x;
  const int lane = tid & 63, wv = tid >> 6;
  const int wm = wv >> 1, wn = wv & 1;
  const int l15 = lane & 15, l4 = lane >> 4;
  const int row0 = blockIdx.x * 128, col0 = blockIdx.y * 128;
  const int srow = lane >> 2;          // staging: lane -> row-in-seg
  const int scol = (lane & 3) * 8;     //          col (ushort)

  f4v acc[4][4];
#pragma unroll
  for (int i = 0; i < 4; ++i)
#pragma unroll
    for (int j = 0; j < 4; ++j) acc[i][j] = f4v{0.f, 0.f, 0.f, 0.f};

  auto stage = [&](int k0, int bsel) {
#pragma unroll
    for (int i = 0; i < 2; ++i) {
      int s = wv * 2 + i;              // 8 segs of 1KB each for A and for B
      gload16(&A[(size_t)(row0 + s * 16 + srow) * K + k0 + scol], &a_lds[bsel][s * 512]);
      gload16(&B[(size_t)(col0 + s * 16 + srow) * K + k0 + scol], &b_lds[bsel][s * 512]);
    }
  };

  stage(0, 0);
  int cur = 0;
  for (int k0 = 0; k0 < K; k0 += 32) {
    __syncthreads();                    // drains vmcnt for buf[cur] + prior reads
    if (k0 + 32 < K) stage(k0 + 32, cur ^ 1);
    s8v af[4], bfr[4];
#pragma unroll
    for (int mi = 0; mi < 4; ++mi)
      af[mi] = *reinterpret_cast<const s8v*>(&a_lds[cur][(wm * 64 + mi * 16 + l15) * 32 + 8 * l4]);
#pragma unroll
    for (int ni = 0; ni < 4; ++ni)
      bfr[ni] = *reinterpret_cast<const s8v*>(&b_lds[cur][(wn * 64 + ni * 16 + l15) * 32 + 8 * l4]);
#pragma unroll
    for (int mi = 0; mi < 4; ++mi)
#pragma unroll
      for (int ni = 0; ni < 4; ++ni) acc[mi][ni] = mfma16(af[mi], bfr[ni], acc[mi][ni]);
    cur ^= 1;
  }

#pragma unroll
  for (int mi = 0; mi < 4; ++mi)
#pragma unroll
    for (int ni = 0; ni < 4; ++ni)
#pragma unroll
      for (int j = 0; j < 4; ++j) {
        int r = row0 + wm * 64 + mi * 16 + l4 * 4 + j;   // C/D: row=(lane>>4)*4+reg
        int cl = col0 + wn * 64 + ni * 16 + l15;          //      col=lane&15
        if (BF16OUT)
          reinterpret_cast<ushort*>(C)[(size_t)r * N + cl] = f2b(acc[mi][ni][j]);
        else
          reinterpret_cast<float*>(C)[(size_t)r * N + cl] = acc[mi][ni][j];
      }
}

// ---------------------------------------------------------------- RMSNorm(cq,ckv) + RoPE(k_rope)
__global__ __launch_bounds__(256) void norm_rope1_kernel(
    const float* __restrict__ g1, const float* __restrict__ wq, const float* __restrict__ wkv,
    const float* __restrict__ freqs, ushort* __restrict__ nq, ushort* __restrict__ nkv,
    ushort* __restrict__ kro) {
  const int m = blockIdx.x;       // 0..4095 = b*2048+s
  const int s = m & 2047;
  const int tid = threadIdx.x;
  __shared__ float red[4];
  const float* row = g1 + (size_t)m * 1152;

  float v0 = row[tid], v1 = row[tid + 256];
  float ss = v0 * v0 + v1 * v1;
#pragma unroll
  for (int off = 32; off > 0; off >>= 1) ss += __shfl_down(ss, off);
  if ((tid & 63) == 0) red[tid >> 6] = ss;
  __syncthreads();
  float r = rsqrtf((red[0] + red[1] + red[2] + red[3]) * (1.0f / 512.0f) + 1e-6f);
  nq[(size_t)m * 512 + tid] = f2b(v0 * r * wq[tid]);
  nq[(size_t)m * 512 + tid + 256] = f2b(v1 * r * wq[tid + 256]);

  float u0 = row[512 + tid], u1 = row[512 + tid + 256];
  float ss2 = u0 * u0 + u1 * u1;
#pragma unroll
  for (int off = 32; off > 0; off >>= 1) ss2 += __shfl_down(ss2, off);
  __syncthreads();
  if ((tid & 63) == 0) red[tid >> 6] = ss2;
  __syncthreads();
  float r2 = rsqrtf((red[0] + red[1] + red[2] + red[3]) * (1.0f / 512.0f) + 1e-6f);
  nkv[(size_t)m * 512 + tid] = f2b(u0 * r2 * wkv[tid]);
  nkv[(size_t)m * 512 + tid + 256] = f2b(u1 * r2 * wkv[tid + 256]);

  if (tid < 32) {
    float x0 = row[1024 + 2 * tid], x1 = row[1024 + 2 * tid + 1];
    float c = freqs[s * 64 + 2 * tid], sn = freqs[s * 64 + 2 * tid + 1];
    kro[(size_t)m * 64 + 2 * tid] = f2b((x0 * c - x1 * sn) * (1.0f / 16.0f));
    kro[(size_t)m * 64 + 2 * tid + 1] = f2b((x0 * sn + x1 * c) * (1.0f / 16.0f));
  }
}

// ---------------------------------------------------------------- RoPE on q_rope (in-place)
__global__ void rope_q_kernel(ushort* __restrict__ g2q, const float* __restrict__ freqs) {
  int idx = blockIdx.x * 256 + threadIdx.x;  // 4096*16*32
  int m = idx >> 9;
  int rem = idx & 511;
  int h = rem >> 5, j = rem & 31;
  int s = m & 2047;
  size_t base = (size_t)m * 3072 + 2048 + h * 64 + 2 * j;
  ushort2 pr = *reinterpret_cast<ushort2*>(&g2q[base]);
  float x0 = b2f(pr.x), x1 = b2f(pr.y);
  float c = freqs[s * 64 + 2 * j], sn = freqs[s * 64 + 2 * j + 1];
  ushort2 o;
  o.x = f2b(x0 * c - x1 * sn);
  o.y = f2b(x0 * sn + x1 * c);
  *reinterpret_cast<ushort2*>(&g2q[base]) = o;
}

// ---------------------------------------------------------------- V transpose -> vT (B,H,128,S)
__global__ __launch_bounds__(256) void transpose_v_kernel(const ushort* __restrict__ g2kv,
                                                          ushort* __restrict__ vT) {
  int blk = blockIdx.x;          // B*H * (S/64) * (128/64) = 2048
  int bh = blk >> 6;
  int rem = blk & 63;
  int st = rem >> 1, dt = rem & 1;
  int b = bh >> 4, h = bh & 15;
  __shared__ ushort t[64][72];
  int tid = threadIdx.x;
#pragma unroll
  for (int it = 0; it < 2; ++it) {
    int c = tid + it * 256;
    int sl = c >> 3, cc = (c & 7) * 8;
    *reinterpret_cast<uint4*>(&t[sl][cc]) = *reinterpret_cast<const uint4*>(
        &g2kv[(size_t)(b * 2048 + st * 64 + sl) * 4096 + 2048 + h * 128 + dt * 64 + cc]);
  }
  __syncthreads();
#pragma unroll
  for (int it = 0; it < 2; ++it) {
    int c = tid + it * 256;
    int dl = c >> 3, cc = (c & 7) * 8;
    ushort tmp[8];
#pragma unroll
    for (int e = 0; e < 8; ++e) tmp[e] = t[cc + e][dl];
    *reinterpret_cast<uint4*>(&vT[(size_t)(bh * 128 + dt * 64 + dl) * 2048 + st * 64 + cc]) =
        *reinterpret_cast<uint4*>(tmp);
  }
}

// ---------------------------------------------------------------- causal flash attention
// QBLK=128, 8 waves x 16 q-rows, KVBLK=64, K/V double-buffered via global_load_lds
// (linear LDS + both-sides XOR swizzle), one barrier per KV tile, LPT qt order.
__global__ __launch_bounds__(512) void attn_kernel(const ushort* __restrict__ q,      // 4096x3072
                                                   const ushort* __restrict__ knope,  // 4096x4096
                                                   const ushort* __restrict__ kro,    // 4096x64
                                                   const ushort* __restrict__ vT,     // (B*H*128)x2048
                                                   ushort* __restrict__ out) {        // 4096x2048
  const int lid = blockIdx.x;               // 512 blocks
  const int bh = lid & 31;
  const int qt = 15 - (lid >> 5);           // heavy-first (LPT) over 16 q-tiles
  const int b = bh >> 4, h = bh & 15;
  const int tid = threadIdx.x, lane = tid & 63, w = tid >> 6;
  const int l15 = lane & 15, l4 = lane >> 4;

  __shared__ ushort kbuf[2][64 * 192];      // 24KB/buf: [key][192] linear, swizzled
  __shared__ ushort vbuf[2][128 * 64];      // 16KB/buf: [d][64key] linear, swizzled
  __shared__ ushort p_lds[8][16][72];       // per-wave P (16q x 64k, +8 pad)

  // Q fragments (A-operand): row = lane&15, k-chunk at 8*(lane>>4)
  s8v qf[6];
  {
    const size_t qbase = (size_t)(b * 2048 + qt * 128 + w * 16 + l15) * 3072;
#pragma unroll
    for (int kc = 0; kc < 4; ++kc)
      qf[kc] = *reinterpret_cast<const s8v*>(&q[qbase + h * 128 + kc * 32 + 8 * l4]);
#pragma unroll
    for (int kc = 4; kc < 6; ++kc)
      qf[kc] = *reinterpret_cast<const s8v*>(&q[qbase + 2048 + h * 64 + (kc - 4) * 32 + 8 * l4]);
  }

  f4v oacc[8];
#pragma unroll
  for (int i = 0; i < 8; ++i) oacc[i] = f4v{0.f, 0.f, 0.f, 0.f};
  float m_r[4] = {-INFINITY, -INFINITY, -INFINITY, -INFINITY};
  float l_r[4] = {0.f, 0.f, 0.f, 0.f};
  const float scale = 0.07216878364870323f;  // 1/sqrt(192)
  const int nkt = 2 * qt + 2;
  const int kbase = b * 2048;

  // stage tile kt into buffer bsel. K logical [row<64][col<192] byte o=row*384+col*2,
  // physical p = o ^ ((row&7)<<4) (XOR stays within row: 384 % 128 == 0).
  // V logical [d<128][key<64] byte o=d*128+key*2, physical p = o ^ ((d&7)<<4).
  // gload_lds writes linear physical; source computed from inverse swizzle (rule #21).
  auto stage = [&](int kt, int bsel) {
    const int krow0 = kbase + kt * 64;
#pragma unroll
    for (int i = 0; i < 3; ++i) {           // K: 24 segs of 1KB, 3 per wave
      int s = w * 3 + i;
      int p = s * 1024 + lane * 16;
      int row = p / 384;
      int col = ((p ^ ((row & 7) << 4)) - row * 384) >> 1;   // ushort col, mult of 8
      const ushort* src = (col < 128)
          ? &knope[(size_t)(krow0 + row) * 4096 + h * 128 + col]
          : &kro[(size_t)(krow0 + row) * 64 + (col - 128)];
      gload16(src, &kbuf[bsel][s * 512]);
    }
#pragma unroll
    for (int i = 0; i < 2; ++i) {           // V: 16 segs of 1KB, 2 per wave
      int s = w * 2 + i;
      int p = s * 1024 + lane * 16;
      int d = p >> 7;
      int key = ((p ^ ((d & 7) << 4)) & 127) >> 1;
      gload16(&vT[(size_t)(bh * 128 + d) * 2048 + kt * 64 + key], &vbuf[bsel][s * 512]);
    }
  };

  stage(0, 0);
  int cur = 0;
  for (int kt = 0; kt < nkt; ++kt) {
    __syncthreads();                         // drains vmcnt(0): buf[cur] ready; prior reads done
    if (kt + 1 < nkt) stage(kt + 1, cur ^ 1);
    const char* kb = (const char*)kbuf[cur];
    const char* vb = (const char*)vbuf[cur];

    // S = Q K^T  (16 q x 64 keys per wave)
    f4v sacc[4];
#pragma unroll
    for (int nb = 0; nb < 4; ++nb) {
      sacc[nb] = f4v{0.f, 0.f, 0.f, 0.f};
      const int row = nb * 16 + l15;
      const int sw = (row & 7) << 4;
#pragma unroll
      for (int kc = 0; kc < 6; ++kc) {
        s8v bfr = *reinterpret_cast<const s8v*>(kb + row * 384 + ((kc * 64 + l4 * 16) ^ sw));
        sacc[nb] = mfma16(qf[kc], bfr, sacc[nb]);
      }
    }
    // scale + causal mask (only the two diagonal tiles need it)
    const int qrow0 = qt * 128 + w * 16 + l4 * 4;
#pragma unroll
    for (int nb = 0; nb < 4; ++nb) {
      int key = kt * 64 + nb * 16 + l15;
#pragma unroll
      for (int j = 0; j < 4; ++j) {
        float sv = sacc[nb][j] * scale;
        if (kt >= 2 * qt && key > qrow0 + j) sv = -INFINITY;
        sacc[nb][j] = sv;
      }
    }
    // online softmax: row max over 64 keys (4 accs + 16-lane butterfly)
    float mx[4];
#pragma unroll
    for (int j = 0; j < 4; ++j)
      mx[j] = fmaxf(fmaxf(sacc[0][j], sacc[1][j]), fmaxf(sacc[2][j], sacc[3][j]));
#pragma unroll
    for (int off = 1; off < 16; off <<= 1)
#pragma unroll
      for (int j = 0; j < 4; ++j) mx[j] = fmaxf(mx[j], __shfl_xor(mx[j], off));
    float al[4], rs[4];
#pragma unroll
    for (int j = 0; j < 4; ++j) {
      float mnew = fmaxf(m_r[j], mx[j]);
      al[j] = __expf(m_r[j] - mnew);
      m_r[j] = mnew;
      rs[j] = 0.f;
    }
#pragma unroll
    for (int nb = 0; nb < 4; ++nb)
#pragma unroll
      for (int j = 0; j < 4; ++j) {
        float p = __expf(sacc[nb][j] - m_r[j]);
        sacc[nb][j] = p;
        rs[j] += p;
      }
#pragma unroll
    for (int off = 1; off < 16; off <<= 1)
#pragma unroll
      for (int j = 0; j < 4; ++j) rs[j] += __shfl_xor(rs[j], off);
#pragma unroll
    for (int j = 0; j < 4; ++j) l_r[j] = l_r[j] * al[j] + rs[j];
    // P -> LDS (wave-private; acc layout -> A-operand layout)
#pragma unroll
    for (int nb = 0; nb < 4; ++nb)
#pragma unroll
      for (int j = 0; j < 4; ++j)
        p_lds[w][l4 * 4 + j][nb * 16 + l15] = f2b(sacc[nb][j]);
    // rescale O
#pragma unroll
    for (int nv = 0; nv < 8; ++nv)
#pragma unroll
      for (int j = 0; j < 4; ++j) oacc[nv][j] *= al[j];
    // O += P V  (V read swizzled)
#pragma unroll
    for (int kc2 = 0; kc2 < 2; ++kc2) {
      s8v pf = *reinterpret_cast<const s8v*>(&p_lds[w][l15][kc2 * 32 + 8 * l4]);
#pragma unroll
      for (int nv = 0; nv < 8; ++nv) {
        const int d = nv * 16 + l15;
        s8v vf = *reinterpret_cast<const s8v*>(vb + d * 128 + ((kc2 * 64 + l4 * 16) ^ ((d & 7) << 4)));
        oacc[nv] = mfma16(pf, vf, oacc[nv]);
      }
    }
    cur ^= 1;
  }

  // epilogue: normalize + store (B,S,H*128) bf16
#pragma unroll
  for (int j = 0; j < 4; ++j) {
    float inv = 1.0f / l_r[j];
    int m = b * 2048 + qt * 128 + w * 16 + l4 * 4 + j;
#pragma unroll
    for (int nv = 0; nv < 8; ++nv)
      out[(size_t)m * 2048 + h * 128 + nv * 16 + l15] = f2b(oacc[nv][j] * inv);
  }
}

// ---------------------------------------------------------------- launch
// Workspace layout (lifetime-aliased, peak 96.5 MiB):
//   [ 0,32M)  g2kv (steps 5-8)   overlay: g1 fp32 18M (steps 2-3)
//   [32,56M)  g2q  (steps 4-8)   overlay: xbf 16M @32M, w1 4.5M @48M (steps 0-2)
//   [56,72M)  vT   (steps 7-8)   overlay: nq 4M @56M, nkv 4M @60M, w2q 3M @64M, w2kv 4M @67M
//   [72,88M)  att  (steps 8-9)
//   [88,96M)  wpj  (steps 0-9)
//   [96,96.5M) kro (steps 3-8)
extern "C" void kernel_launch(void* const* d_in, const int* in_sizes, int n_in,
                              void* d_out, int out_size, void* d_ws, size_t ws_size,
                              hipStream_t stream) {
  const float* x       = (const float*)d_in[0];
  const float* freqs   = (const float*)d_in[2];
  const float* w_cq    = (const float*)d_in[3];
  const float* w_qnorm = (const float*)d_in[4];
  const float* w_dqn   = (const float*)d_in[5];
  const float* w_dqr   = (const float*)d_in[6];
  const float* w_ckv   = (const float*)d_in[7];
  const float* w_kvnorm= (const float*)d_in[8];
  const float* w_dkn   = (const float*)d_in[9];
  const float* w_dv    = (const float*)d_in[10];
  const float* w_krope = (const float*)d_in[11];
  const float* w_proj  = (const float*)d_in[12];
  float* out = (float*)d_out;

  char* ws = (char*)d_ws;
  const size_t MB = 1ull << 20;
  ushort* g2kv = (ushort*)(ws + 0);
  float*  g1   = (float*) (ws + 0);
  ushort* g2q  = (ushort*)(ws + 32 * MB);
  ushort* xbf  = (ushort*)(ws + 32 * MB);
  ushort* w1   = (ushort*)(ws + 48 * MB);
  ushort* vT   = (ushort*)(ws + 56 * MB);
  ushort* nq   = (ushort*)(ws + 56 * MB);
  ushort* nkv  = (ushort*)(ws + 60 * MB);
  ushort* w2q  = (ushort*)(ws + 64 * MB);
  ushort* w2kv = (ushort*)(ws + 67 * MB);
  ushort* att  = (ushort*)(ws + 72 * MB);
  ushort* wpj  = (ushort*)(ws + 88 * MB);
  ushort* kro  = (ushort*)(ws + 96 * MB);

  auto cast = [&](const float* s, ushort* d, int n) {
    cast_f2b_kernel<<<(n / 4 + 255) / 256, 256, 0, stream>>>(s, d, n / 4);
  };
  // step 0: casts
  cast(x, xbf, 4096 * 2048);
  cast(w_cq, w1, 512 * 2048);
  cast(w_ckv, w1 + 512 * 2048, 512 * 2048);
  cast(w_krope, w1 + 1024 * 2048, 64 * 2048);
  fill_zero_kernel<<<64, 256, 0, stream>>>(w1 + 1088 * 2048, 64 * 2048 / 8);  // N-pad rows
  cast(w_dqn, w2q, 2048 * 512);
  cast(w_dqr, w2q + 2048 * 512, 1024 * 512);
  cast(w_dkn, w2kv, 2048 * 512);
  cast(w_dv, w2kv + 2048 * 512, 2048 * 512);
  cast(w_proj, wpj, 2048 * 2048);

  // step 2: fused compress GEMM  [cq | ckv | krope]
  gemm_bt<false><<<dim3(32, 9), 256, 0, stream>>>(xbf, w1, g1, 4096, 1152, 2048);
  // step 3: RMSNorm + k_rope RoPE
  norm_rope1_kernel<<<4096, 256, 0, stream>>>(g1, w_qnorm, w_kvnorm, freqs, nq, nkv, kro);
  // step 4: Q decompress
  gemm_bt<true><<<dim3(32, 24), 256, 0, stream>>>(nq, w2q, g2q, 4096, 3072, 512);
  // step 5: KV decompress
  gemm_bt<true><<<dim3(32, 32), 256, 0, stream>>>(nkv, w2kv, g2kv, 4096, 4096, 512);
  // step 6: Q RoPE (in place)
  rope_q_kernel<<<8192, 256, 0, stream>>>(g2q, freqs);
  // step 7: V transpose for attention B-operand
  transpose_v_kernel<<<2048, 256, 0, stream>>>(g2kv, vT);
  // step 8: causal flash attention
  attn_kernel<<<512, 512, 0, stream>>>(g2q, g2kv, kro, vT, att);
  // step 9: output projection
  gemm_bt<false><<<dim3(32, 16), 256, 0, stream>>>(att, wpj, out, 4096, 2048, 2048);
}